// Round 14
// baseline (83.836 us; speedup 1.0000x reference)
//
#include <hip/hip_runtime.h>
#include <math.h>

#define N_ROWS 262144
#define D 128
#define C 64
#define CSTRIDE 4608      // padded per-class index slot (count ~4096 + 8 sigma)
#define BB 64             // build blocks; 4096 rows each
#define FB 2048           // fused blocks = 64 classes x 32 octants; 128 CE rows each
#define FT 512
#define TMAX 5            // ceil(CSTRIDE / (1024 groups per class))
#define OCTW 132          // per-block partial: 128 sums + cnt + sq + pad

// ws layout (4-byte units)
#define OFF_IDX    0                          // int[C*CSTRIDE]
#define OFF_CNT    (C * CSTRIDE)              // int[C]
#define OFF_CEB    (OFF_CNT + C)              // float[FB]
#define OFF_OCT    (OFF_CEB + FB)             // float[FB*OCTW]

// asm-issued 32B gather: compiler cannot sink/serialize these
__device__ __forceinline__ void gload8(float4& a, float4& b, const float* p) {
  asm volatile("global_load_dwordx4 %0, %2, off\n\t"
               "global_load_dwordx4 %1, %2, off offset:16"
               : "=&v"(a), "=&v"(b)
               : "v"(p));
}

// ---------------- K1: one-shot index build (hist+scan+scatter fused) --------
__global__ __launch_bounds__(1024) void build_kernel(
    const int* __restrict__ labels, int* __restrict__ idx,
    int* __restrict__ cnts) {
  __shared__ int sH[C];
  __shared__ int sBase[C];
  const int t = threadIdx.x, b = blockIdx.x;
  if (t < C) sH[t] = 0;
  __syncthreads();
  const int row = b * 4096 + t * 4;
  const int4 l = *(const int4*)(labels + row);
  const int p0 = atomicAdd(&sH[l.x], 1);
  const int p1 = atomicAdd(&sH[l.y], 1);
  const int p2 = atomicAdd(&sH[l.z], 1);
  const int p3 = atomicAdd(&sH[l.w], 1);
  __syncthreads();
  if (t < C) sBase[t] = atomicAdd(&cnts[t], sH[t]);
  __syncthreads();
  idx[l.x * CSTRIDE + sBase[l.x] + p0] = row;
  idx[l.y * CSTRIDE + sBase[l.y] + p1] = row + 1;
  idx[l.z * CSTRIDE + sBase[l.z] + p2] = row + 2;
  idx[l.w * CSTRIDE + sBase[l.w] + p3] = row + 3;
}

// ---------------- K2: fused CE + class-gather, parity-staggered -------------
__global__ __launch_bounds__(FT, 4) void fused_kernel(
    const float* __restrict__ emb, const float* __restrict__ logits,
    const int* __restrict__ labels, const int* __restrict__ idxArr,
    const int* __restrict__ cnts, float* __restrict__ ceB,
    float* __restrict__ oct) {
  __shared__ float sCe[8];
  __shared__ float sR[8][OCTW];

  const int tid = threadIdx.x;
  const int wave = tid >> 6, lane = tid & 63;
  const int g = lane >> 4, lp = lane & 15;
  const int b = blockIdx.x;

  // ---- CE phase: 128 sequential rows, proven streaming skeleton ----
  auto ce_phase = [&]() {
    const int rowBase = b * 128 + wave * 16 + g;
    float ce_acc = 0.f;
    float4 tA, tB;
    int labA = 0, labB = 0;
    tA = *(const float4*)(logits + (size_t)rowBase * C + lp * 4);
    labA = labels[rowBase];
    tB = tA;
#pragma unroll
    for (int it = 0; it < 4; ++it) {
      const float4 t4 = (it & 1) ? tB : tA;
      const int lab = (it & 1) ? labB : labA;
      if (it + 1 < 4) {
        const int row = rowBase + (it + 1) * 4;
        if (it & 1) {
          tA = *(const float4*)(logits + (size_t)row * C + lp * 4);
          labA = labels[row];
        } else {
          tB = *(const float4*)(logits + (size_t)row * C + lp * 4);
          labB = labels[row];
        }
      }
      float p = __expf(t4.x) + __expf(t4.y) + __expf(t4.z) + __expf(t4.w);
      float tl = 0.f;
      if ((lab >> 2) == lp) {
        const int k = lab & 3;
        tl = k == 0 ? t4.x : k == 1 ? t4.y : k == 2 ? t4.z : t4.w;
      }
      p += __shfl_xor(p, 1);  tl += __shfl_xor(tl, 1);
      p += __shfl_xor(p, 2);  tl += __shfl_xor(tl, 2);
      p += __shfl_xor(p, 4);  tl += __shfl_xor(tl, 4);
      p += __shfl_xor(p, 8);  tl += __shfl_xor(tl, 8);
      if (lp == 0) ce_acc += __logf(p) - tl;
    }
    ce_acc += __shfl_xor(ce_acc, 16);
    ce_acc += __shfl_xor(ce_acc, 32);
    if (lane == 0) sCe[wave] = ce_acc;
    __syncthreads();
    if (tid == 0) {
      float s = 0.f;
#pragma unroll
      for (int w = 0; w < 8; ++w) s += sCe[w];
      ceB[b] = s;
    }
  };

  // ---- proto phase: asm-forced depth-5 gather pipeline (depth == TMAX) ----
  auto proto_phase = [&]() {
    const int c = b >> 5, o = b & 31;
    const int gg = o * 32 + wave * 4 + g;    // group slot in class: 0..1023
    const int n = cnts[c];
    const int nm1 = (n > 0) ? n - 1 : 0;
    const int* ip = idxArr + c * CSTRIDE;

    int rI[TMAX];
#pragma unroll
    for (int t = 0; t < TMAX; ++t) {
      const int e = gg + 1024 * t;
      rI[t] = ip[e < nm1 ? e : nm1];
    }
    // force index loads complete BEFORE the pipeline, so the compiler never
    // inserts a draining vmcnt(0) between our asm loads
#pragma unroll
    for (int t = 0; t < TMAX; ++t) asm volatile("" :: "v"(rI[t]));
    __builtin_amdgcn_sched_barrier(0);

    float4 s0a, s0b, s1a, s1b, s2a, s2b, s3a, s3b, s4a, s4b;
    gload8(s0a, s0b, emb + (size_t)rI[0] * D + lp * 8);
    gload8(s1a, s1b, emb + (size_t)rI[1] * D + lp * 8);
    gload8(s2a, s2b, emb + (size_t)rI[2] * D + lp * 8);
    gload8(s3a, s3b, emb + (size_t)rI[3] * D + lp * 8);
    gload8(s4a, s4b, emb + (size_t)rI[4] * D + lp * 8);

    float4 accA = {0.f, 0.f, 0.f, 0.f}, accB = {0.f, 0.f, 0.f, 0.f};
    float cnt = 0.f, sq = 0.f;

    auto consume = [&](const float4 ea, const float4 eb, const int t) {
      float ss = ea.x * ea.x + ea.y * ea.y + ea.z * ea.z + ea.w * ea.w +
                 eb.x * eb.x + eb.y * eb.y + eb.z * eb.z + eb.w * eb.w;
      ss += __shfl_xor(ss, 1);
      ss += __shfl_xor(ss, 2);
      ss += __shfl_xor(ss, 4);
      ss += __shfl_xor(ss, 8);
      const float inv = 1.0f / fmaxf(sqrtf(ss), 1e-12f);
      const bool valid = (gg + 1024 * t) < n;
      const float sc = valid ? inv : 0.f;    // validity folded into the scale
      accA.x += ea.x * sc;  accA.y += ea.y * sc;
      accA.z += ea.z * sc;  accA.w += ea.w * sc;
      accB.x += eb.x * sc;  accB.y += eb.y * sc;
      accB.z += eb.z * sc;  accB.w += eb.w * sc;
      if (lp == 0) {
        cnt += valid ? 1.f : 0.f;
        sq += valid ? ss * inv * inv : 0.f;
      }
    };

// counted vmcnt drain: 8,6,4,2,0 (10 loads in flight at start)
#define PSTEP(T, NW, SA, SB)                          \
    asm volatile("s_waitcnt vmcnt(" #NW ")");         \
    __builtin_amdgcn_sched_barrier(0);                \
    consume(SA, SB, T);

    PSTEP(0, 8, s0a, s0b)
    PSTEP(1, 6, s1a, s1b)
    PSTEP(2, 4, s2a, s2b)
    PSTEP(3, 2, s3a, s3b)
    PSTEP(4, 0, s4a, s4b)
#undef PSTEP

    // cross-group reduce (groups share the lp->dim map)
#pragma unroll
    for (int off = 16; off <= 32; off <<= 1) {
      accA.x += __shfl_xor(accA.x, off);  accA.y += __shfl_xor(accA.y, off);
      accA.z += __shfl_xor(accA.z, off);  accA.w += __shfl_xor(accA.w, off);
      accB.x += __shfl_xor(accB.x, off);  accB.y += __shfl_xor(accB.y, off);
      accB.z += __shfl_xor(accB.z, off);  accB.w += __shfl_xor(accB.w, off);
      cnt += __shfl_xor(cnt, off);
      sq += __shfl_xor(sq, off);
    }

    if (lane < 16) {
      *(float4*)&sR[wave][lp * 8] = accA;
      *(float4*)&sR[wave][lp * 8 + 4] = accB;
    }
    if (lane == 0) { sR[wave][128] = cnt; sR[wave][129] = sq; }
    __syncthreads();
    if (tid < 130) {
      float s = 0.f;
#pragma unroll
      for (int w = 0; w < 8; ++w) s += sR[w][tid];
      oct[(size_t)b * OCTW + tid] = s;
    }
  };

  // parity stagger: half the chip streams logits while half gathers emb
  if (b & 1) { ce_phase(); __syncthreads(); proto_phase(); }
  else       { proto_phase(); __syncthreads(); ce_phase(); }
}

// ---------------- K3: class stats + CE sum + final scalar (one block) -------
__global__ __launch_bounds__(1024) void classfinal_kernel(
    const float* __restrict__ oct, const float* __restrict__ ceB,
    float* __restrict__ out) {
  __shared__ float sPer[C], sVal[C], sCe[16];
  const int tid = threadIdx.x, wave = tid >> 6, lane = tid & 63;

  // CE: 2048 block partials over 1024 threads
  float ce = ceB[tid] + ceB[tid + 1024];
#pragma unroll
  for (int off = 1; off < 64; off <<= 1) ce += __shfl_xor(ce, off);
  if (lane == 0) sCe[wave] = ce;

  // wave w handles classes 4w..4w+3; lane owns dims lane and 64+lane
#pragma unroll
  for (int q = 0; q < 4; ++q) {
    const int c = wave * 4 + q;
    float s0 = 0.f, s1 = 0.f, n = 0.f, sq = 0.f;
#pragma unroll
    for (int o = 0; o < 32; ++o) {
      const float* f = oct + (size_t)(c * 32 + o) * OCTW;
      s0 += f[lane];
      s1 += f[64 + lane];
      n += f[128];
      sq += f[129];
    }
    const float safe = fmaxf(n, 1.f);
    const float mu0 = s0 / safe, mu1 = s1 / safe;
    float msq = mu0 * mu0 + mu1 * mu1;
#pragma unroll
    for (int off = 1; off < 64; off <<= 1) msq += __shfl_xor(msq, off);
    if (lane == 0) {
      const float ssd = sq - n * msq;
      const bool valid = n > 1.f;
      sPer[c] = valid ? ssd / safe : 0.f;
      sVal[c] = valid ? 1.f : 0.f;
    }
  }
  __syncthreads();
  if (tid == 0) {
    float pr = 0.f, nv = 0.f, c2 = 0.f;
#pragma unroll
    for (int c = 0; c < C; ++c) { pr += sPer[c]; nv += sVal[c]; }
#pragma unroll
    for (int w = 0; w < 16; ++w) c2 += sCe[w];
    out[0] = 0.5f * (c2 / (float)N_ROWS) + 0.5f * (pr / fmaxf(nv, 1.f));
  }
}

extern "C" void kernel_launch(void* const* d_in, const int* in_sizes, int n_in,
                              void* d_out, int out_size, void* d_ws, size_t ws_size,
                              hipStream_t stream) {
  const float* emb = (const float*)d_in[0];
  const float* logits = (const float*)d_in[1];
  const int* labels = (const int*)d_in[2];
  int* wsi = (int*)d_ws;
  float* wsf = (float*)d_ws;
  float* out = (float*)d_out;

  int* idx = wsi + OFF_IDX;
  int* cnts = wsi + OFF_CNT;
  float* ceB = wsf + OFF_CEB;
  float* oct = wsf + OFF_OCT;

  hipMemsetAsync(cnts, 0, C * sizeof(int), stream);
  build_kernel<<<BB, 1024, 0, stream>>>(labels, idx, cnts);
  fused_kernel<<<FB, FT, 0, stream>>>(emb, logits, labels, idx, cnts, ceB, oct);
  classfinal_kernel<<<1, 1024, 0, stream>>>(oct, ceB, out);
}

// Round 15
// 51.001 us; speedup vs baseline: 1.6438x; 1.6438x over previous
//
#include <hip/hip_runtime.h>
#include <math.h>

#define N_ROWS 262144
#define D 128
#define C 64
#define CSTRIDE 4608      // padded per-class index slot (count ~4096 + 8 sigma)
#define BB 64             // build blocks; 4096 rows each
#define FB 2048           // fused blocks = 64 classes x 32 octants; 128 CE rows each
#define FT 512
#define TMAX 5            // ceil(CSTRIDE / (1024 groups per class))
#define OCTW 132          // per-block partial: 128 sums + cnt + sq + pad

// ws layout (4-byte units)
#define OFF_IDX    0                          // int[C*CSTRIDE]
#define OFF_CNT    (C * CSTRIDE)              // int[C]
#define OFF_CEB    (OFF_CNT + C)              // float[FB]
#define OFF_OCT    (OFF_CEB + FB)             // float[FB*OCTW]
#define OFF_RES    (OFF_OCT + FB * OCTW)      // float[2*C]
#define OFF_CES    (OFF_RES + 2 * C)          // float[C]

// asm-issued 32B gather: compiler cannot sink/serialize these
__device__ __forceinline__ void gload8(float4& a, float4& b, const float* p) {
  asm volatile("global_load_dwordx4 %0, %2, off\n\t"
               "global_load_dwordx4 %1, %2, off offset:16"
               : "=&v"(a), "=&v"(b)
               : "v"(p));
}

// ---------------- K1: one-shot index build (hist+scan+scatter fused) --------
__global__ __launch_bounds__(1024) void build_kernel(
    const int* __restrict__ labels, int* __restrict__ idx,
    int* __restrict__ cnts) {
  __shared__ int sH[C];
  __shared__ int sBase[C];
  const int t = threadIdx.x, b = blockIdx.x;
  if (t < C) sH[t] = 0;
  __syncthreads();
  const int row = b * 4096 + t * 4;
  const int4 l = *(const int4*)(labels + row);
  const int p0 = atomicAdd(&sH[l.x], 1);
  const int p1 = atomicAdd(&sH[l.y], 1);
  const int p2 = atomicAdd(&sH[l.z], 1);
  const int p3 = atomicAdd(&sH[l.w], 1);
  __syncthreads();
  if (t < C) sBase[t] = atomicAdd(&cnts[t], sH[t]);
  __syncthreads();
  idx[l.x * CSTRIDE + sBase[l.x] + p0] = row;
  idx[l.y * CSTRIDE + sBase[l.y] + p1] = row + 1;
  idx[l.z * CSTRIDE + sBase[l.z] + p2] = row + 2;
  idx[l.w * CSTRIDE + sBase[l.w] + p3] = row + 3;
}

// ---------------- K2: fused CE + class-gather, parity-staggered -------------
__global__ __launch_bounds__(FT, 4) void fused_kernel(
    const float* __restrict__ emb, const float* __restrict__ logits,
    const int* __restrict__ labels, const int* __restrict__ idxArr,
    const int* __restrict__ cnts, float* __restrict__ ceB,
    float* __restrict__ oct) {
  __shared__ float sCe[8];
  __shared__ float sR[8][OCTW];

  const int tid = threadIdx.x;
  const int wave = tid >> 6, lane = tid & 63;
  const int g = lane >> 4, lp = lane & 15;
  const int b = blockIdx.x;

  // ---- CE phase: 128 sequential rows, proven streaming skeleton ----
  auto ce_phase = [&]() {
    const int rowBase = b * 128 + wave * 16 + g;
    float ce_acc = 0.f;
    float4 tA, tB;
    int labA = 0, labB = 0;
    tA = *(const float4*)(logits + (size_t)rowBase * C + lp * 4);
    labA = labels[rowBase];
    tB = tA;
#pragma unroll
    for (int it = 0; it < 4; ++it) {
      const float4 t4 = (it & 1) ? tB : tA;
      const int lab = (it & 1) ? labB : labA;
      if (it + 1 < 4) {
        const int row = rowBase + (it + 1) * 4;
        if (it & 1) {
          tA = *(const float4*)(logits + (size_t)row * C + lp * 4);
          labA = labels[row];
        } else {
          tB = *(const float4*)(logits + (size_t)row * C + lp * 4);
          labB = labels[row];
        }
      }
      float p = __expf(t4.x) + __expf(t4.y) + __expf(t4.z) + __expf(t4.w);
      float tl = 0.f;
      if ((lab >> 2) == lp) {
        const int k = lab & 3;
        tl = k == 0 ? t4.x : k == 1 ? t4.y : k == 2 ? t4.z : t4.w;
      }
      p += __shfl_xor(p, 1);  tl += __shfl_xor(tl, 1);
      p += __shfl_xor(p, 2);  tl += __shfl_xor(tl, 2);
      p += __shfl_xor(p, 4);  tl += __shfl_xor(tl, 4);
      p += __shfl_xor(p, 8);  tl += __shfl_xor(tl, 8);
      if (lp == 0) ce_acc += __logf(p) - tl;
    }
    ce_acc += __shfl_xor(ce_acc, 16);
    ce_acc += __shfl_xor(ce_acc, 32);
    if (lane == 0) sCe[wave] = ce_acc;
    __syncthreads();
    if (tid == 0) {
      float s = 0.f;
#pragma unroll
      for (int w = 0; w < 8; ++w) s += sCe[w];
      ceB[b] = s;
    }
  };

  // ---- proto phase: asm-forced depth-5 gather pipeline (depth == TMAX) ----
  auto proto_phase = [&]() {
    const int c = b >> 5, o = b & 31;
    const int gg = o * 32 + wave * 4 + g;    // group slot in class: 0..1023
    const int n = cnts[c];
    const int nm1 = (n > 0) ? n - 1 : 0;
    const int* ip = idxArr + c * CSTRIDE;

    int rI[TMAX];
#pragma unroll
    for (int t = 0; t < TMAX; ++t) {
      const int e = gg + 1024 * t;
      rI[t] = ip[e < nm1 ? e : nm1];
    }
    // force index loads complete BEFORE the pipeline, so the compiler never
    // inserts a draining vmcnt(0) between our asm loads
#pragma unroll
    for (int t = 0; t < TMAX; ++t) asm volatile("" :: "v"(rI[t]));
    __builtin_amdgcn_sched_barrier(0);

    float4 s0a, s0b, s1a, s1b, s2a, s2b, s3a, s3b, s4a, s4b;
    gload8(s0a, s0b, emb + (size_t)rI[0] * D + lp * 8);
    gload8(s1a, s1b, emb + (size_t)rI[1] * D + lp * 8);
    gload8(s2a, s2b, emb + (size_t)rI[2] * D + lp * 8);
    gload8(s3a, s3b, emb + (size_t)rI[3] * D + lp * 8);
    gload8(s4a, s4b, emb + (size_t)rI[4] * D + lp * 8);

    float4 accA = {0.f, 0.f, 0.f, 0.f}, accB = {0.f, 0.f, 0.f, 0.f};
    float cnt = 0.f, sq = 0.f;

    auto consume = [&](const float4 ea, const float4 eb, const int t) {
      float ss = ea.x * ea.x + ea.y * ea.y + ea.z * ea.z + ea.w * ea.w +
                 eb.x * eb.x + eb.y * eb.y + eb.z * eb.z + eb.w * eb.w;
      ss += __shfl_xor(ss, 1);
      ss += __shfl_xor(ss, 2);
      ss += __shfl_xor(ss, 4);
      ss += __shfl_xor(ss, 8);
      const float inv = 1.0f / fmaxf(sqrtf(ss), 1e-12f);
      const bool valid = (gg + 1024 * t) < n;
      const float sc = valid ? inv : 0.f;    // validity folded into the scale
      accA.x += ea.x * sc;  accA.y += ea.y * sc;
      accA.z += ea.z * sc;  accA.w += ea.w * sc;
      accB.x += eb.x * sc;  accB.y += eb.y * sc;
      accB.z += eb.z * sc;  accB.w += eb.w * sc;
      if (lp == 0) {
        cnt += valid ? 1.f : 0.f;
        sq += valid ? ss * inv * inv : 0.f;
      }
    };

// counted vmcnt drain: 8,6,4,2,0 (10 loads in flight at start)
#define PSTEP(T, NW, SA, SB)                          \
    asm volatile("s_waitcnt vmcnt(" #NW ")");         \
    __builtin_amdgcn_sched_barrier(0);                \
    consume(SA, SB, T);

    PSTEP(0, 8, s0a, s0b)
    PSTEP(1, 6, s1a, s1b)
    PSTEP(2, 4, s2a, s2b)
    PSTEP(3, 2, s3a, s3b)
    PSTEP(4, 0, s4a, s4b)
#undef PSTEP

    // cross-group reduce (groups share the lp->dim map)
#pragma unroll
    for (int off = 16; off <= 32; off <<= 1) {
      accA.x += __shfl_xor(accA.x, off);  accA.y += __shfl_xor(accA.y, off);
      accA.z += __shfl_xor(accA.z, off);  accA.w += __shfl_xor(accA.w, off);
      accB.x += __shfl_xor(accB.x, off);  accB.y += __shfl_xor(accB.y, off);
      accB.z += __shfl_xor(accB.z, off);  accB.w += __shfl_xor(accB.w, off);
      cnt += __shfl_xor(cnt, off);
      sq += __shfl_xor(sq, off);
    }

    if (lane < 16) {
      *(float4*)&sR[wave][lp * 8] = accA;
      *(float4*)&sR[wave][lp * 8 + 4] = accB;
    }
    if (lane == 0) { sR[wave][128] = cnt; sR[wave][129] = sq; }
    __syncthreads();
    if (tid < 130) {
      float s = 0.f;
#pragma unroll
      for (int w = 0; w < 8; ++w) s += sR[w][tid];
      oct[(size_t)b * OCTW + tid] = s;
    }
  };

  // parity stagger: half the chip streams logits while half gathers emb
  if (b & 1) { ce_phase(); __syncthreads(); proto_phase(); }
  else       { proto_phase(); __syncthreads(); ce_phase(); }
}

// ---------------- K3: per-class stats + per-class CE partial ----------------
__global__ __launch_bounds__(128) void class_kernel(
    const float* __restrict__ oct, const float* __restrict__ ceB,
    float* __restrict__ res, float* __restrict__ ceS) {
  __shared__ float sM[2];
  const int c = blockIdx.x, t = threadIdx.x;
  float s = 0.f, n = 0.f, sq = 0.f;
#pragma unroll
  for (int o = 0; o < 32; ++o) {
    const float* f = oct + (size_t)(c * 32 + o) * OCTW;
    s += f[t];
    n += f[128];
    sq += f[129];
  }
  const float safe = fmaxf(n, 1.f);
  const float mu = s / safe;
  float msq = mu * mu;
#pragma unroll
  for (int off = 1; off < 64; off <<= 1) msq += __shfl_xor(msq, off);
  if ((t & 63) == 0) sM[t >> 6] = msq;

  // reduce this class's 32 CE block-partials (wave 0, lanes 0..31)
  if (t < 32) {
    float ce = ceB[c * 32 + t];
    ce += __shfl_xor(ce, 1);
    ce += __shfl_xor(ce, 2);
    ce += __shfl_xor(ce, 4);
    ce += __shfl_xor(ce, 8);
    ce += __shfl_xor(ce, 16);
    if (t == 0) ceS[c] = ce;
  }
  __syncthreads();
  if (t == 0) {
    const float ssd = sq - n * (sM[0] + sM[1]);
    const bool valid = n > 1.f;
    res[c] = valid ? ssd / safe : 0.f;
    res[C + c] = valid ? 1.f : 0.f;
  }
}

// ---------------- K4: final scalar (one wave, 256 floats in) ----------------
__global__ __launch_bounds__(64) void final_kernel(
    const float* __restrict__ ceS, const float* __restrict__ res,
    float* __restrict__ out) {
  const int t = threadIdx.x;
  float ce = ceS[t], pr = res[t], nv = res[C + t];
#pragma unroll
  for (int off = 1; off < 64; off <<= 1) {
    ce += __shfl_xor(ce, off);
    pr += __shfl_xor(pr, off);
    nv += __shfl_xor(nv, off);
  }
  if (t == 0)
    out[0] = 0.5f * (ce / (float)N_ROWS) + 0.5f * (pr / fmaxf(nv, 1.f));
}

extern "C" void kernel_launch(void* const* d_in, const int* in_sizes, int n_in,
                              void* d_out, int out_size, void* d_ws, size_t ws_size,
                              hipStream_t stream) {
  const float* emb = (const float*)d_in[0];
  const float* logits = (const float*)d_in[1];
  const int* labels = (const int*)d_in[2];
  int* wsi = (int*)d_ws;
  float* wsf = (float*)d_ws;
  float* out = (float*)d_out;

  int* idx = wsi + OFF_IDX;
  int* cnts = wsi + OFF_CNT;
  float* ceB = wsf + OFF_CEB;
  float* oct = wsf + OFF_OCT;
  float* res = wsf + OFF_RES;
  float* ceS = wsf + OFF_CES;

  hipMemsetAsync(cnts, 0, C * sizeof(int), stream);
  build_kernel<<<BB, 1024, 0, stream>>>(labels, idx, cnts);
  fused_kernel<<<FB, FT, 0, stream>>>(emb, logits, labels, idx, cnts, ceB, oct);
  class_kernel<<<C, 128, 0, stream>>>(oct, ceB, res, ceS);
  final_kernel<<<1, 64, 0, stream>>>(ceS, res, out);
}

// Round 16
// 50.568 us; speedup vs baseline: 1.6579x; 1.0086x over previous
//
#include <hip/hip_runtime.h>
#include <math.h>

#define N_ROWS 262144
#define D 128
#define C 64
#define CSTRIDE 4608      // padded per-class index slot (count ~4096 + 8 sigma)
#define BB 64             // build blocks; 4096 rows each
#define FB 2048           // fused blocks = 64 classes x 32 octants; 128 CE rows each
#define FT 512
#define TMAX 5            // ceil(CSTRIDE / (1024 groups per class))
#define OCTW 132          // per-block partial: 128 sums + cnt + sq + pad

// ws layout (4-byte units)
#define OFF_IDX    0                          // int[C*CSTRIDE]
#define OFF_CNT    (C * CSTRIDE)              // int[C]
#define OFF_CEB    (OFF_CNT + C)              // float[FB]
#define OFF_OCT    (OFF_CEB + FB)             // float[FB*OCTW]
#define OFF_RES    (OFF_OCT + FB * OCTW)      // float[2*C]
#define OFF_CES    (OFF_RES + 2 * C)          // float[C]

// asm-issued 32B gather: compiler cannot sink/serialize these
__device__ __forceinline__ void gload8(float4& a, float4& b, const float* p) {
  asm volatile("global_load_dwordx4 %0, %2, off\n\t"
               "global_load_dwordx4 %1, %2, off offset:16"
               : "=&v"(a), "=&v"(b)
               : "v"(p));
}

// ---------------- K1: one-shot index build (hist+scan+scatter fused) --------
__global__ __launch_bounds__(1024) void build_kernel(
    const int* __restrict__ labels, int* __restrict__ idx,
    int* __restrict__ cnts) {
  __shared__ int sH[C];
  __shared__ int sBase[C];
  const int t = threadIdx.x, b = blockIdx.x;
  if (t < C) sH[t] = 0;
  __syncthreads();
  const int row = b * 4096 + t * 4;
  const int4 l = *(const int4*)(labels + row);
  const int p0 = atomicAdd(&sH[l.x], 1);
  const int p1 = atomicAdd(&sH[l.y], 1);
  const int p2 = atomicAdd(&sH[l.z], 1);
  const int p3 = atomicAdd(&sH[l.w], 1);
  __syncthreads();
  if (t < C) sBase[t] = atomicAdd(&cnts[t], sH[t]);
  __syncthreads();
  idx[l.x * CSTRIDE + sBase[l.x] + p0] = row;
  idx[l.y * CSTRIDE + sBase[l.y] + p1] = row + 1;
  idx[l.z * CSTRIDE + sBase[l.z] + p2] = row + 2;
  idx[l.w * CSTRIDE + sBase[l.w] + p3] = row + 3;
}

// ---------------- K2: fused CE + class-gather, parity-staggered -------------
__global__ __launch_bounds__(FT, 4) void fused_kernel(
    const float* __restrict__ emb, const float* __restrict__ logits,
    const int* __restrict__ labels, const int* __restrict__ idxArr,
    const int* __restrict__ cnts, float* __restrict__ ceB,
    float* __restrict__ oct) {
  __shared__ float sCe[8];
  __shared__ float sR[8][OCTW];

  const int tid = threadIdx.x;
  const int wave = tid >> 6, lane = tid & 63;
  const int g = lane >> 4, lp = lane & 15;
  const int b = blockIdx.x;

  // ---- CE phase: 8-lane groups (8 logits/lane), DPP-friendly xor 1/2/4 ----
  auto ce_phase = [&]() {
    const int g8 = lane >> 3, lq = lane & 7;   // 8 groups of 8 lanes
    const int rowBase = b * 128 + wave * 16 + g8;
    float ce_acc = 0.f;
    float4 aA, bA, aB, bB;
    int labA = 0, labB = 0;
    {
      const float* lg = logits + (size_t)rowBase * C + lq * 8;
      aA = *(const float4*)lg;  bA = *(const float4*)(lg + 4);
      labA = labels[rowBase];
      aB = aA; bB = bA;
    }
#pragma unroll
    for (int it = 0; it < 2; ++it) {
      const float4 ta = it ? aB : aA;
      const float4 tb = it ? bB : bA;
      const int lab = it ? labB : labA;
      if (it == 0) {                           // prefetch second row
        const int row = rowBase + 8;
        const float* lg = logits + (size_t)row * C + lq * 8;
        aB = *(const float4*)lg;  bB = *(const float4*)(lg + 4);
        labB = labels[row];
      }
      float p = __expf(ta.x) + __expf(ta.y) + __expf(ta.z) + __expf(ta.w) +
                __expf(tb.x) + __expf(tb.y) + __expf(tb.z) + __expf(tb.w);
      float tl = 0.f;
      if ((lab >> 3) == lq) {
        const int k = lab & 7;
        tl = k == 0 ? ta.x : k == 1 ? ta.y : k == 2 ? ta.z : k == 3 ? ta.w
           : k == 4 ? tb.x : k == 5 ? tb.y : k == 6 ? tb.z : tb.w;
      }
      p += __shfl_xor(p, 1);  tl += __shfl_xor(tl, 1);
      p += __shfl_xor(p, 2);  tl += __shfl_xor(tl, 2);
      p += __shfl_xor(p, 4);  tl += __shfl_xor(tl, 4);
      if (lq == 0) ce_acc += __logf(p) - tl;
    }
    // sum the 8 group partials (lanes 0,8,...,56) into lane 0
    ce_acc += __shfl_xor(ce_acc, 8);
    ce_acc += __shfl_xor(ce_acc, 16);
    ce_acc += __shfl_xor(ce_acc, 32);
    if (lane == 0) sCe[wave] = ce_acc;
    __syncthreads();
    if (tid == 0) {
      float s = 0.f;
#pragma unroll
      for (int w = 0; w < 8; ++w) s += sCe[w];
      ceB[b] = s;
    }
  };

  // ---- proto phase: asm-forced depth-5 gather pipeline (depth == TMAX) ----
  auto proto_phase = [&]() {
    const int c = b >> 5, o = b & 31;
    const int gg = o * 32 + wave * 4 + g;    // group slot in class: 0..1023
    const int n = cnts[c];
    const int nm1 = (n > 0) ? n - 1 : 0;
    const int* ip = idxArr + c * CSTRIDE;

    int rI[TMAX];
#pragma unroll
    for (int t = 0; t < TMAX; ++t) {
      const int e = gg + 1024 * t;
      rI[t] = ip[e < nm1 ? e : nm1];
    }
    // force index loads complete BEFORE the pipeline, so the compiler never
    // inserts a draining vmcnt(0) between our asm loads
#pragma unroll
    for (int t = 0; t < TMAX; ++t) asm volatile("" :: "v"(rI[t]));
    __builtin_amdgcn_sched_barrier(0);

    float4 s0a, s0b, s1a, s1b, s2a, s2b, s3a, s3b, s4a, s4b;
    gload8(s0a, s0b, emb + (size_t)rI[0] * D + lp * 8);
    gload8(s1a, s1b, emb + (size_t)rI[1] * D + lp * 8);
    gload8(s2a, s2b, emb + (size_t)rI[2] * D + lp * 8);
    gload8(s3a, s3b, emb + (size_t)rI[3] * D + lp * 8);
    gload8(s4a, s4b, emb + (size_t)rI[4] * D + lp * 8);

    float4 accA = {0.f, 0.f, 0.f, 0.f}, accB = {0.f, 0.f, 0.f, 0.f};
    float cnt = 0.f, sq = 0.f;

    auto consume = [&](const float4 ea, const float4 eb, const int t) {
      float ss = ea.x * ea.x + ea.y * ea.y + ea.z * ea.z + ea.w * ea.w +
                 eb.x * eb.x + eb.y * eb.y + eb.z * eb.z + eb.w * eb.w;
      ss += __shfl_xor(ss, 1);
      ss += __shfl_xor(ss, 2);
      ss += __shfl_xor(ss, 4);
      ss += __shfl_xor(ss, 8);
      const float inv = 1.0f / fmaxf(sqrtf(ss), 1e-12f);
      const bool valid = (gg + 1024 * t) < n;
      const float sc = valid ? inv : 0.f;    // validity folded into the scale
      accA.x += ea.x * sc;  accA.y += ea.y * sc;
      accA.z += ea.z * sc;  accA.w += ea.w * sc;
      accB.x += eb.x * sc;  accB.y += eb.y * sc;
      accB.z += eb.z * sc;  accB.w += eb.w * sc;
      if (lp == 0) {
        cnt += valid ? 1.f : 0.f;
        sq += valid ? ss * inv * inv : 0.f;
      }
    };

// counted vmcnt drain: 8,6,4,2,0 (10 loads in flight at start)
#define PSTEP(T, NW, SA, SB)                          \
    asm volatile("s_waitcnt vmcnt(" #NW ")");         \
    __builtin_amdgcn_sched_barrier(0);                \
    consume(SA, SB, T);

    PSTEP(0, 8, s0a, s0b)
    PSTEP(1, 6, s1a, s1b)
    PSTEP(2, 4, s2a, s2b)
    PSTEP(3, 2, s3a, s3b)
    PSTEP(4, 0, s4a, s4b)
#undef PSTEP

    // cross-group reduce (groups share the lp->dim map)
#pragma unroll
    for (int off = 16; off <= 32; off <<= 1) {
      accA.x += __shfl_xor(accA.x, off);  accA.y += __shfl_xor(accA.y, off);
      accA.z += __shfl_xor(accA.z, off);  accA.w += __shfl_xor(accA.w, off);
      accB.x += __shfl_xor(accB.x, off);  accB.y += __shfl_xor(accB.y, off);
      accB.z += __shfl_xor(accB.z, off);  accB.w += __shfl_xor(accB.w, off);
      cnt += __shfl_xor(cnt, off);
      sq += __shfl_xor(sq, off);
    }

    if (lane < 16) {
      *(float4*)&sR[wave][lp * 8] = accA;
      *(float4*)&sR[wave][lp * 8 + 4] = accB;
    }
    if (lane == 0) { sR[wave][128] = cnt; sR[wave][129] = sq; }
    __syncthreads();
    if (tid < 130) {
      float s = 0.f;
#pragma unroll
      for (int w = 0; w < 8; ++w) s += sR[w][tid];
      oct[(size_t)b * OCTW + tid] = s;
    }
  };

  // parity stagger: half the chip streams logits while half gathers emb
  if (b & 1) { ce_phase(); __syncthreads(); proto_phase(); }
  else       { proto_phase(); __syncthreads(); ce_phase(); }
}

// ---------------- K3: per-class stats + per-class CE partial ----------------
__global__ __launch_bounds__(128) void class_kernel(
    const float* __restrict__ oct, const float* __restrict__ ceB,
    float* __restrict__ res, float* __restrict__ ceS) {
  __shared__ float sM[2];
  const int c = blockIdx.x, t = threadIdx.x;
  float s = 0.f, n = 0.f, sq = 0.f;
#pragma unroll
  for (int o = 0; o < 32; ++o) {
    const float* f = oct + (size_t)(c * 32 + o) * OCTW;
    s += f[t];
    n += f[128];
    sq += f[129];
  }
  const float safe = fmaxf(n, 1.f);
  const float mu = s / safe;
  float msq = mu * mu;
#pragma unroll
  for (int off = 1; off < 64; off <<= 1) msq += __shfl_xor(msq, off);
  if ((t & 63) == 0) sM[t >> 6] = msq;

  // reduce this class's 32 CE block-partials (wave 0, lanes 0..31)
  if (t < 32) {
    float ce = ceB[c * 32 + t];
    ce += __shfl_xor(ce, 1);
    ce += __shfl_xor(ce, 2);
    ce += __shfl_xor(ce, 4);
    ce += __shfl_xor(ce, 8);
    ce += __shfl_xor(ce, 16);
    if (t == 0) ceS[c] = ce;
  }
  __syncthreads();
  if (t == 0) {
    const float ssd = sq - n * (sM[0] + sM[1]);
    const bool valid = n > 1.f;
    res[c] = valid ? ssd / safe : 0.f;
    res[C + c] = valid ? 1.f : 0.f;
  }
}

// ---------------- K4: final scalar (one wave, 256 floats in) ----------------
__global__ __launch_bounds__(64) void final_kernel(
    const float* __restrict__ ceS, const float* __restrict__ res,
    float* __restrict__ out) {
  const int t = threadIdx.x;
  float ce = ceS[t], pr = res[t], nv = res[C + t];
#pragma unroll
  for (int off = 1; off < 64; off <<= 1) {
    ce += __shfl_xor(ce, off);
    pr += __shfl_xor(pr, off);
    nv += __shfl_xor(nv, off);
  }
  if (t == 0)
    out[0] = 0.5f * (ce / (float)N_ROWS) + 0.5f * (pr / fmaxf(nv, 1.f));
}

extern "C" void kernel_launch(void* const* d_in, const int* in_sizes, int n_in,
                              void* d_out, int out_size, void* d_ws, size_t ws_size,
                              hipStream_t stream) {
  const float* emb = (const float*)d_in[0];
  const float* logits = (const float*)d_in[1];
  const int* labels = (const int*)d_in[2];
  int* wsi = (int*)d_ws;
  float* wsf = (float*)d_ws;
  float* out = (float*)d_out;

  int* idx = wsi + OFF_IDX;
  int* cnts = wsi + OFF_CNT;
  float* ceB = wsf + OFF_CEB;
  float* oct = wsf + OFF_OCT;
  float* res = wsf + OFF_RES;
  float* ceS = wsf + OFF_CES;

  hipMemsetAsync(cnts, 0, C * sizeof(int), stream);
  build_kernel<<<BB, 1024, 0, stream>>>(labels, idx, cnts);
  fused_kernel<<<FB, FT, 0, stream>>>(emb, logits, labels, idx, cnts, ceB, oct);
  class_kernel<<<C, 128, 0, stream>>>(oct, ceB, res, ceS);
  final_kernel<<<1, 64, 0, stream>>>(ceS, res, out);
}